// Round 1
// baseline (512.545 us; speedup 1.0000x reference)
//
#include <hip/hip_runtime.h>
#include <math.h>

namespace {
constexpr int Kc = 1024;   // num_embeddings
constexpr int Dd = 64;     // embedding_dim

// numpy pairwise_sum of squares, n=64, exact numpy op order:
//   tmp[d] = fl(a[d]*a[d]) elementwise (rounded BEFORE summing -> contract off)
//   r[j]=tmp[j]; for i=8..56 step 8: r[j]+=tmp[i+j];
//   res = ((r0+r1)+(r2+r3)) + ((r4+r5)+(r6+r7))
__device__ inline float np_sumsq64(const float* __restrict__ a) {
#pragma clang fp contract(off)
    float r[8];
    #pragma unroll
    for (int j = 0; j < 8; ++j) r[j] = a[j] * a[j];
    #pragma unroll
    for (int i = 8; i < 64; i += 8) {
        #pragma unroll
        for (int j = 0; j < 8; ++j) {
            float s = a[i + j] * a[i + j];   // rounded square
            r[j] = r[j] + s;                 // no FMA fusion (contract off)
        }
    }
    return ((r[0] + r[1]) + (r[2] + r[3])) + ((r[4] + r[5]) + (r[6] + r[7]));
}

// ---- precompute ee[k] = np.sum(emb*emb, axis=1) bitwise; also zero hist ----
__global__ void k_ee(const float* __restrict__ emb, float* __restrict__ ee,
                     unsigned int* __restrict__ hist) {
    int k = blockIdx.x * blockDim.x + threadIdx.x;
    ee[k] = np_sumsq64(emb + (size_t)k * Dd);
    hist[k] = 0u;
}

// ---- main: 1024 blocks x 256 thr; 64 pixels/block, 4 wave-uniform k-pieces ----
// v2: 4-way entry interleave (4 independent sequential-fmaf chains -> ILP hides
//     FMA dep latency and amortizes scalar-load lgkmcnt waits), plus per-wave
//     start rotation to desynchronize co-resident waves' s_load stall bursts.
//     Argmin uses exact (dist, index) lexicographic compare so iteration order
//     cannot change the selected index.
__global__ __launch_bounds__(256, 4) void k_main(
    const float* __restrict__ inputs, const float* __restrict__ emb,
    const float* __restrict__ ee_g, float* __restrict__ quant,
    float* __restrict__ enc, float* __restrict__ idx_out,
    unsigned int* __restrict__ hist, float* __restrict__ partials)
{
    __shared__ float sb[4][64];
    __shared__ int   si[4][64];

    const int tid = threadIdx.x;
    const int p = __builtin_amdgcn_readfirstlane(tid >> 6);  // wave-uniform piece
    const int l = tid & 63;                                  // pixel within block
    const int n = blockIdx.x * 64 + l;
    const int b = n >> 10;
    const int hw = n & 1023;

    // x[d] = inputs[b, d, h, w]  (coalesced across the wave for each d)
    const float* xin = inputs + (size_t)b * (Dd * 1024) + hw;
    float x[Dd];
    #pragma unroll
    for (int d = 0; d < Dd; ++d) x[d] = xin[d * 1024];

    const float xx = np_sumsq64(x);   // numpy-order fp32 ||x||^2

    // block zeroes its own 64 encoding rows (16384 float4), hidden under FMAs
    float4* enc4 = (float4*)enc + (size_t)blockIdx.x * 16384 + tid;

    float best = INFINITY;
    int i1 = 0;
    const int k0 = p * 256;
    // desync: rotate quad start per (piece, block) so co-resident waves on a
    // SIMD don't convoy on the same scalar-load latency window
    const int rot = ((p + (int)blockIdx.x) & 3) * 16;

    for (int qq = 0; qq < 64; ++qq) {
        const int q = (qq + rot) & 63;
        const int kb = __builtin_amdgcn_readfirstlane(k0 + q * 4);
        const float* __restrict__ eb = emb + (size_t)kb * Dd;

        // 4 independent sequential fp32 FMA chains (per-entry order preserved:
        // each g_u is a single accumulator stepping d = 0..63 in order)
        float g0 = 0.f, g1 = 0.f, g2 = 0.f, g3 = 0.f;
        #pragma unroll
        for (int d = 0; d < Dd; ++d) {
            const float xd = x[d];
            g0 = fmaf(xd, eb[d],       g0);
            g1 = fmaf(xd, eb[d + 64],  g1);
            g2 = fmaf(xd, eb[d + 128], g2);
            g3 = fmaf(xd, eb[d + 192], g3);
        }

        // numpy: dist = fl( fl(xx + ee[k]) - 2*g )  (x2 exact; one rounding each)
        const float A0 = xx + ee_g[kb];
        const float A1 = xx + ee_g[kb + 1];
        const float A2 = xx + ee_g[kb + 2];
        const float A3 = xx + ee_g[kb + 3];
        const float d0 = fmaf(-2.f, g0, A0);
        const float d1 = fmaf(-2.f, g1, A1);
        const float d2 = fmaf(-2.f, g2, A2);
        const float d3 = fmaf(-2.f, g3, A3);

        // exact first-index tie-break (order-independent)
        bool lt;
        lt = (d0 < best) || (d0 == best && (kb + 0) < i1);
        best = lt ? d0 : best;  i1 = lt ? kb + 0 : i1;
        lt = (d1 < best) || (d1 == best && (kb + 1) < i1);
        best = lt ? d1 : best;  i1 = lt ? kb + 1 : i1;
        lt = (d2 < best) || (d2 == best && (kb + 2) < i1);
        best = lt ? d2 : best;  i1 = lt ? kb + 2 : i1;
        lt = (d3 < best) || (d3 == best && (kb + 3) < i1);
        best = lt ? d3 : best;  i1 = lt ? kb + 3 : i1;

        // 256 KB zero-fill interleaved: one float4 store per quad iteration
        *enc4 = float4{0.f, 0.f, 0.f, 0.f};
        enc4 += 256;
    }

    sb[p][l] = best; si[p][l] = i1;
    __syncthreads();   // also drains this block's enc zero-fill stores

    if (tid < 64) {    // wave 0: merge 4 pieces with exact (dist,index) compare
        best = INFINITY; i1 = 0x7fffffff;
        #pragma unroll
        for (int q = 0; q < 4; ++q) {
            float s = sb[q][l];
            int   i = si[q][l];
            bool lt = (s < best) || (s == best && i < i1);
            best = lt ? s : best;
            i1   = lt ? i : i1;
        }

        // quantized output: gather codebook row, store NCHW (coalesced per d)
        {
            const float4* eb = (const float4*)(emb + (size_t)i1 * Dd);
            float* qout = quant + (size_t)b * (Dd * 1024) + hw;
            #pragma unroll
            for (int i = 0; i < Dd / 4; ++i) {
                float4 v = eb[i];
                qout[(i * 4 + 0) * 1024] = v.x;
                qout[(i * 4 + 1) * 1024] = v.y;
                qout[(i * 4 + 2) * 1024] = v.z;
                qout[(i * 4 + 3) * 1024] = v.w;
            }
        }

        idx_out[n] = (float)i1;
        atomicAdd(hist + i1, 1u);

        // one-hot scatter into this block's own (already-zeroed) rows
        enc[(size_t)n * Kc + i1] = 1.0f;

        // loss partial: dist_min == ||x - e*||^2 (includes ||x||^2 already)
        float v = best;
        #pragma unroll
        for (int off = 32; off > 0; off >>= 1) v += __shfl_down(v, off, 64);
        if (l == 0) partials[blockIdx.x] = v;
    }
}

// ---- final: perplexity from histogram, loss from partials (1 sync total) ----
__global__ __launch_bounds__(1024) void k_fin(
    const unsigned int* __restrict__ hist, const float* __restrict__ partials,
    float* __restrict__ loss_out, float* __restrict__ perp_out)
{
    __shared__ double sent[16];
    __shared__ double spar[16];
    const int tid = threadIdx.x;

    double pv = (double)hist[tid] * (1.0 / 65536.0);
    double e = pv * log(pv + 1e-10);
    double s = (double)partials[tid];

    #pragma unroll
    for (int off = 32; off > 0; off >>= 1) {
        e += __shfl_down(e, off, 64);
        s += __shfl_down(s, off, 64);
    }
    if ((tid & 63) == 0) { sent[tid >> 6] = e; spar[tid >> 6] = s; }
    __syncthreads();

    if (tid == 0) {
        double ent = 0.0, sum = 0.0;
        #pragma unroll
        for (int w = 0; w < 16; ++w) { ent += sent[w]; sum += spar[w]; }
        double perp = exp(-ent);
        double mean = sum * (1.0 / 4194304.0);   // sum ||x-e||^2 / (N*D)
        double loss = 1.25 * mean + 0.1 * (1024.0 - perp) / 1024.0;
        loss_out[0] = (float)loss;
        perp_out[0] = (float)perp;
    }
}
} // namespace

extern "C" void kernel_launch(void* const* d_in, const int* in_sizes, int n_in,
                              void* d_out, int out_size, void* d_ws, size_t ws_size,
                              hipStream_t stream)
{
    const float* inputs = (const float*)d_in[0];   // [64,64,32,32] fp32
    const float* emb    = (const float*)d_in[1];   // [1024,64] fp32
    float* out = (float*)d_out;

    float* loss_out = out;                            // [1]
    float* quant    = out + 1;                        // [64,64,32,32]
    float* perp_out = out + 1 + 4194304;              // [1]
    float* enc      = out + 2 + 4194304;              // [65536,1024]
    float* idx_out  = out + 2 + 4194304 + 67108864;   // [65536,1]

    unsigned int* hist = (unsigned int*)d_ws;         // [1024] u32
    float* partials    = (float*)d_ws + 1024;         // [1024] f32 (fully overwritten)
    float* ee          = (float*)d_ws + 2048;         // [1024] f32

    k_ee<<<Kc / 256, 256, 0, stream>>>(emb, ee, hist);
    k_main<<<65536 / 64, 256, 0, stream>>>(inputs, emb, ee, quant, enc, idx_out, hist, partials);
    k_fin<<<1, 1024, 0, stream>>>(hist, partials, loss_out, perp_out);
}